// Round 4
// baseline (167.240 us; speedup 1.0000x reference)
//
#include <hip/hip_runtime.h>

// DPQ embedding, MI355X. N=131072 tokens, EMB=128, D=8 subspaces x SUB=16, K=128 codes.
// Pipeline:
//  k1_stats:  gather x rows, accumulate per-block moment stats (G, Sx, h, Sn, S2)
//  k2a/k2b:   deterministic two-stage tree-reduce of block partials (in-place)
//  k3_final:  stats + centroids -> alpha[k], beta[d][k]  (BN folded into affine score)
//  k4_main:   per (token, d-pair): dot over 128 codes via SGPR (s_load) centroids,
//             argmax, write both selected centroids as one 128B line.
//             NOTE: no min-waves force in launch_bounds -- R3's (256,8) capped VGPR
//             at 64 and the compiler shuttled x[] through AGPRs (VGPR_Count=20,
//             ~2x VALU instructions). Let the allocator breathe.

constexpr int NTOK = 131072;   // 1024*128
constexpr int ST   = 2320;     // stats stride (2312 used, padded)
constexpr float EPS = 0.001f;

// stats layout: G: d*256 + s*16 + s'  (2048)
//               Sx: 2048 + d*16 + s   (128)
//               h : 2176 + d*16 + s   (128)
//               S2: 2304 + d          (8)    -> 2312 total

__global__ __launch_bounds__(256) void k1_stats(const int* __restrict__ ids,
                                                const float* __restrict__ wemb,
                                                float* __restrict__ partials,
                                                int tpb)
{
    __shared__ float xs[32][132];   // 32 tokens x 128 floats, padded to 132
    __shared__ float nrm[32][8];
    const int t = threadIdx.x;
    const int b = blockIdx.x;

    float g[4][4];
#pragma unroll
    for (int i = 0; i < 4; ++i)
#pragma unroll
        for (int j = 0; j < 4; ++j) g[i][j] = 0.f;
    float sx = 0.f, hh = 0.f, s2 = 0.f;

    const int d_g = t >> 4;                 // t<128: Gram task (d, 4x4 tile)
    const int r0  = ((t >> 2) & 3) << 2;
    const int c0  = (t & 3) << 2;
    const int u   = t & 127;                // t>=128: (d,s) task
    const int d_s = u >> 4;
    const int s_s = u & 15;

    const int nchunks = tpb >> 5;
    for (int ch = 0; ch < nchunks; ++ch) {
        const int n0 = b * tpb + ch * 32;
        // ---- load 32 token rows (coalesced: 32 lanes x float4 = one 512B row) ----
#pragma unroll
        for (int rep = 0; rep < 4; ++rep) {
            int i = t + rep * 256;
            int n = i >> 5, f = i & 31;
            int id = ids[n0 + n];
            float4 v = *(const float4*)(wemb + (size_t)id * 128 + f * 4);
            *(float4*)(&xs[n][f * 4]) = v;
        }
        __syncthreads();
        // ---- per-(n,d) norms: 256 threads = 32x8 ----
        {
            int n = t >> 3, dd = t & 7;
            const float* xp = &xs[n][dd * 16];
            float4 a = *(const float4*)(xp);
            float4 bq = *(const float4*)(xp + 4);
            float4 c = *(const float4*)(xp + 8);
            float4 dq = *(const float4*)(xp + 12);
            float acc = a.x*a.x + a.y*a.y + a.z*a.z + a.w*a.w;
            acc += bq.x*bq.x + bq.y*bq.y + bq.z*bq.z + bq.w*bq.w;
            acc += c.x*c.x + c.y*c.y + c.z*c.z + c.w*c.w;
            acc += dq.x*dq.x + dq.y*dq.y + dq.z*dq.z + dq.w*dq.w;
            nrm[n][dd] = acc;
        }
        __syncthreads();
        // ---- accumulate stats over the chunk ----
        if (t < 128) {
            for (int n = 0; n < 32; ++n) {
                const float* xp = &xs[n][d_g * 16];
                float4 av = *(const float4*)(xp + r0);
                float4 bv = *(const float4*)(xp + c0);
                float aa[4] = {av.x, av.y, av.z, av.w};
                float bb[4] = {bv.x, bv.y, bv.z, bv.w};
#pragma unroll
                for (int i = 0; i < 4; ++i)
#pragma unroll
                    for (int j = 0; j < 4; ++j)
                        g[i][j] = fmaf(aa[i], bb[j], g[i][j]);
            }
        } else {
            for (int n = 0; n < 32; ++n) {
                float xv = xs[n][d_s * 16 + s_s];
                float nv = nrm[n][d_s];
                sx += xv;
                hh = fmaf(nv, xv, hh);
                if (s_s == 0) s2 = fmaf(nv, nv, s2);
            }
        }
        __syncthreads();
    }
    float* pb = partials + (size_t)b * ST;
    if (t < 128) {
        const int base = d_g * 256;
#pragma unroll
        for (int i = 0; i < 4; ++i)
#pragma unroll
            for (int j = 0; j < 4; ++j)
                pb[base + (r0 + i) * 16 + (c0 + j)] = g[i][j];
    } else {
        pb[2048 + d_s * 16 + s_s] = sx;
        pb[2176 + d_s * 16 + s_s] = hh;
        if (s_s == 0) pb[2304 + d_s] = s2;
    }
}

// ---- stage A: fold nb blocks down to 32, in place. grid (10, 32). ----
__global__ __launch_bounds__(256) void k2a_reduce(float* __restrict__ partials, int nb)
{
    const int idx = blockIdx.x * 256 + threadIdx.x;
    if (idx >= 2312) return;
    const int y = blockIdx.y;          // 0..31
    float acc[8] = {0.f, 0.f, 0.f, 0.f, 0.f, 0.f, 0.f, 0.f};
    int b = y;
    while (b + 7 * 32 < nb) {
#pragma unroll
        for (int u = 0; u < 8; ++u)
            acc[u] += partials[(size_t)(b + u * 32) * ST + idx];
        b += 8 * 32;
    }
    while (b < nb) { acc[0] += partials[(size_t)b * ST + idx]; b += 32; }
    float s = ((acc[0] + acc[1]) + (acc[2] + acc[3]))
            + ((acc[4] + acc[5]) + (acc[6] + acc[7]));
    partials[(size_t)y * ST + idx] = s;
}

// ---- stage B: sum the 32 survivors (L2-resident, fully unrolled). grid 10. ----
__global__ __launch_bounds__(256) void k2b_reduce(const float* __restrict__ partials,
                                                  float* __restrict__ stats)
{
    const int idx = blockIdx.x * 256 + threadIdx.x;
    if (idx >= 2312) return;
    float acc[8] = {0.f, 0.f, 0.f, 0.f, 0.f, 0.f, 0.f, 0.f};
#pragma unroll
    for (int j = 0; j < 4; ++j)
#pragma unroll
        for (int u = 0; u < 8; ++u)
            acc[u] += partials[(size_t)(j * 8 + u) * ST + idx];
    stats[idx] = ((acc[0] + acc[1]) + (acc[2] + acc[3]))
               + ((acc[4] + acc[5]) + (acc[6] + acc[7]));
}

__global__ __launch_bounds__(128) void k3_final(const float* __restrict__ stats,
                                                const float* __restrict__ centroids,
                                                float2* __restrict__ ab)
{
    __shared__ float st[2312];
    const int t = threadIdx.x;
    for (int i = t; i < 2312; i += 128) st[i] = stats[i];
    __syncthreads();
    const int k = t;   // 128 threads, one per code

    double Sn[8], Sn_tot = 0.0, S2_tot = 0.0;
#pragma unroll
    for (int d = 0; d < 8; ++d) {
        double s = 0.0;
        for (int ss = 0; ss < 16; ++ss) s += (double)st[d * 256 + ss * 17];
        Sn[d] = s; Sn_tot += s;
        S2_tot += (double)st[2304 + d];
    }
    double sr = -Sn_tot, sr2 = S2_tot;
    double ncd[8];
    for (int d = 0; d < 8; ++d) {
        const float* cp = centroids + d * 2048 + k * 16;
        float cv[16];
#pragma unroll
        for (int s = 0; s < 16; ++s) cv[s] = cp[s];
        double nc = 0, cdSx = 0, ch = 0, cGc = 0;
        for (int s = 0; s < 16; ++s) {
            nc   += (double)cv[s] * cv[s];
            cdSx += (double)cv[s] * st[2048 + d * 16 + s];
            ch   += (double)cv[s] * st[2176 + d * 16 + s];
            double rd = 0;
            for (int s2i = 0; s2i < 16; ++s2i)
                rd += (double)st[d * 256 + s * 16 + s2i] * cv[s2i];
            cGc += (double)cv[s] * rd;
        }
        ncd[d] = nc;
        sr  += 2.0 * cdSx - (double)NTOK * nc;
        sr2 += 4.0 * cGc + (double)NTOK * nc * nc + 2.0 * nc * Sn[d]
               - 4.0 * ch - 4.0 * nc * cdSx;
    }
    const double M = (double)NTOK * 8.0;
    double mean = sr / M;
    double var  = sr2 / M - mean * mean;
    float alpha = (float)(1.0 / sqrt(var + (double)EPS));
#pragma unroll
    for (int d = 0; d < 8; ++d) {
        float beta = (float)((double)alpha * (-ncd[d] - mean));
        ab[d * 128 + k] = make_float2(2.f * alpha, beta);
    }
}

// One token per thread, one d-PAIR per blockIdx.y (d0=2p, d1=2p+1).
// Two independent 16-FMA chains give ILP=2; centroid & (alpha,beta) reads are
// wave-uniform -> s_load into SGPRs (zero vector-memory in the k loop).
// Output is 32 contiguous floats = one full 128B cache line per thread.
__global__ __launch_bounds__(256) void k4_main(const int* __restrict__ ids,
                                               const float* __restrict__ wemb,
                                               const float* __restrict__ centroids,
                                               const float2* __restrict__ ab,
                                               float* __restrict__ out)
{
    const int t = threadIdx.x;
    const int p = blockIdx.y;               // 0..3
    const int n = blockIdx.x * 256 + t;
    const int d0 = 2 * p;
    const float* cd0 = centroids + (size_t)d0 * 2048;
    const float* cd1 = cd0 + 2048;
    const float2* gb0 = ab + (size_t)d0 * 128;
    const float2* gb1 = gb0 + 128;

    const float* xp = wemb + (size_t)ids[n] * 128 + d0 * 16;
    float x0[16], x1[16];
#pragma unroll
    for (int q = 0; q < 16; q += 4) {
        float4 v = *(const float4*)(xp + q);
        x0[q] = v.x; x0[q + 1] = v.y; x0[q + 2] = v.z; x0[q + 3] = v.w;
    }
#pragma unroll
    for (int q = 0; q < 16; q += 4) {
        float4 v = *(const float4*)(xp + 16 + q);
        x1[q] = v.x; x1[q + 1] = v.y; x1[q + 2] = v.z; x1[q + 3] = v.w;
    }
    float s0 = 0.f, s1 = 0.f;
#pragma unroll
    for (int q = 0; q < 16; ++q) { s0 = fmaf(x0[q], x0[q], s0); s1 = fmaf(x1[q], x1[q], s1); }
    const float nx0 = -0.5f * s0;      // score = 2a*(dot - nx/2) + beta
    const float nx1 = -0.5f * s1;
    float best0 = -3.4e38f, best1 = -3.4e38f;
    int code0 = 0, code1 = 0;

#pragma unroll 2
    for (int k = 0; k < 128; ++k) {
        const float* a0 = cd0 + k * 16;     // wave-uniform -> s_load_dwordx16
        const float* a1 = cd1 + k * 16;
        float acc0 = nx0, acc1 = nx1;
#pragma unroll
        for (int q = 0; q < 16; ++q) {
            acc0 = fmaf(a0[q], x0[q], acc0);
            acc1 = fmaf(a1[q], x1[q], acc1);
        }
        float2 g0 = gb0[k], g1 = gb1[k];    // wave-uniform -> s_load
        float sc0 = fmaf(g0.x, acc0, g0.y);
        float sc1 = fmaf(g1.x, acc1, g1.y);
        bool p0 = sc0 > best0;              // strict > keeps FIRST max (argmax tie rule)
        bool p1 = sc1 > best1;
        best0 = p0 ? sc0 : best0;  code0 = p0 ? k : code0;
        best1 = p1 ? sc1 : best1;  code1 = p1 ? k : code1;
    }

    const float* w0 = cd0 + code0 * 16;     // divergent, but 8KB hot set -> L1
    const float* w1 = cd1 + code1 * 16;
    float* op = out + (size_t)n * 128 + d0 * 16;
#pragma unroll
    for (int q = 0; q < 16; q += 4) {
        float4 cv = *(const float4*)(w0 + q);
        float4 o;
        // match reference: out = x + (c - x) in fp32 (not just c)
        o.x = x0[q + 0] + (cv.x - x0[q + 0]);
        o.y = x0[q + 1] + (cv.y - x0[q + 1]);
        o.z = x0[q + 2] + (cv.z - x0[q + 2]);
        o.w = x0[q + 3] + (cv.w - x0[q + 3]);
        *(float4*)(op + q) = o;
    }
#pragma unroll
    for (int q = 0; q < 16; q += 4) {
        float4 cv = *(const float4*)(w1 + q);
        float4 o;
        o.x = x1[q + 0] + (cv.x - x1[q + 0]);
        o.y = x1[q + 1] + (cv.y - x1[q + 1]);
        o.z = x1[q + 2] + (cv.z - x1[q + 2]);
        o.w = x1[q + 3] + (cv.w - x1[q + 3]);
        *(float4*)(op + 16 + q) = o;
    }
}

extern "C" void kernel_launch(void* const* d_in, const int* in_sizes, int n_in,
                              void* d_out, int out_size, void* d_ws, size_t ws_size,
                              hipStream_t stream)
{
    const int* ids    = (const int*)d_in[0];
    const float* wemb = (const float*)d_in[1];
    const float* cent = (const float*)d_in[2];
    float* out = (float*)d_out;
    float* ws  = (float*)d_ws;

    // choose pass-1 block count by available workspace
    int p1b = 1024;
    if (ws_size < ((size_t)1024 * ST + 2320 + 2048) * 4) p1b = 512;
    if (ws_size < ((size_t)512  * ST + 2320 + 2048) * 4) p1b = 256;
    if (ws_size < ((size_t)256  * ST + 2320 + 2048) * 4) p1b = 128;
    const int tpb = NTOK / p1b;

    float* partials = ws;
    float* stats    = ws + (size_t)p1b * ST;
    float2* ab      = (float2*)(stats + 2320);

    hipLaunchKernelGGL(k1_stats,   dim3(p1b),     dim3(256), 0, stream, ids, wemb, partials, tpb);
    hipLaunchKernelGGL(k2a_reduce, dim3(10, 32),  dim3(256), 0, stream, partials, p1b);
    hipLaunchKernelGGL(k2b_reduce, dim3(10),      dim3(256), 0, stream, partials, stats);
    hipLaunchKernelGGL(k3_final,   dim3(1),       dim3(128), 0, stream, stats, cent, ab);
    hipLaunchKernelGGL(k4_main,    dim3(512, 4),  dim3(256), 0, stream, ids, wemb, cent, ab, out);
}

// Round 5
// 156.316 us; speedup vs baseline: 1.0699x; 1.0699x over previous
//
#include <hip/hip_runtime.h>

// DPQ embedding, MI355X. N=131072 tokens, EMB=128, D=8 subspaces x SUB=16, K=128 codes.
// Pipeline:
//  k1_stats:  gather x rows, accumulate per-block moment stats (G, Sx, h, Sn, S2)
//  k2a/k2b:   deterministic two-stage tree-reduce of block partials (in-place)
//  k3_final:  stats + centroids -> alpha[k], beta[d][k]  (BN folded into affine score)
//  k4_main:   per (token, d-pair): centroids broadcast from LDS (wave-uniform
//             ds_read_b128, conflict-free), 2 independent 16-FMA chains, argmax,
//             one 128B-line write per thread.
// History: R3 SMEM-broadcast 103us (scalar-cache OK for 1 stream); R4 SMEM x2
// streams 126us (lgkmcnt drain + sKcache thrash, VALUBusy 35%). R5 returns to
// LDS broadcast (R2's 55-75% VALUBusy path) with d-pair + high occupancy.

constexpr int NTOK = 131072;   // 1024*128
constexpr int ST   = 2320;     // stats stride (2312 used, padded)
constexpr float EPS = 0.001f;

// stats layout: G: d*256 + s*16 + s'  (2048)
//               Sx: 2048 + d*16 + s   (128)
//               h : 2176 + d*16 + s   (128)
//               S2: 2304 + d          (8)    -> 2312 total

__global__ __launch_bounds__(256) void k1_stats(const int* __restrict__ ids,
                                                const float* __restrict__ wemb,
                                                float* __restrict__ partials,
                                                int tpb)
{
    __shared__ float xs[32][132];   // 32 tokens x 128 floats, padded to 132
    __shared__ float nrm[32][8];
    const int t = threadIdx.x;
    const int b = blockIdx.x;

    float g[4][4];
#pragma unroll
    for (int i = 0; i < 4; ++i)
#pragma unroll
        for (int j = 0; j < 4; ++j) g[i][j] = 0.f;
    float sx = 0.f, hh = 0.f, s2 = 0.f;

    const int d_g = t >> 4;                 // t<128: Gram task (d, 4x4 tile)
    const int r0  = ((t >> 2) & 3) << 2;
    const int c0  = (t & 3) << 2;
    const int u   = t & 127;                // t>=128: (d,s) task
    const int d_s = u >> 4;
    const int s_s = u & 15;

    const int nchunks = tpb >> 5;
    for (int ch = 0; ch < nchunks; ++ch) {
        const int n0 = b * tpb + ch * 32;
        // ---- load 32 token rows (coalesced: 32 lanes x float4 = one 512B row) ----
#pragma unroll
        for (int rep = 0; rep < 4; ++rep) {
            int i = t + rep * 256;
            int n = i >> 5, f = i & 31;
            int id = ids[n0 + n];
            float4 v = *(const float4*)(wemb + (size_t)id * 128 + f * 4);
            *(float4*)(&xs[n][f * 4]) = v;
        }
        __syncthreads();
        // ---- per-(n,d) norms: 256 threads = 32x8 ----
        {
            int n = t >> 3, dd = t & 7;
            const float* xp = &xs[n][dd * 16];
            float4 a = *(const float4*)(xp);
            float4 bq = *(const float4*)(xp + 4);
            float4 c = *(const float4*)(xp + 8);
            float4 dq = *(const float4*)(xp + 12);
            float acc = a.x*a.x + a.y*a.y + a.z*a.z + a.w*a.w;
            acc += bq.x*bq.x + bq.y*bq.y + bq.z*bq.z + bq.w*bq.w;
            acc += c.x*c.x + c.y*c.y + c.z*c.z + c.w*c.w;
            acc += dq.x*dq.x + dq.y*dq.y + dq.z*dq.z + dq.w*dq.w;
            nrm[n][dd] = acc;
        }
        __syncthreads();
        // ---- accumulate stats over the chunk ----
        if (t < 128) {
            for (int n = 0; n < 32; ++n) {
                const float* xp = &xs[n][d_g * 16];
                float4 av = *(const float4*)(xp + r0);
                float4 bv = *(const float4*)(xp + c0);
                float aa[4] = {av.x, av.y, av.z, av.w};
                float bb[4] = {bv.x, bv.y, bv.z, bv.w};
#pragma unroll
                for (int i = 0; i < 4; ++i)
#pragma unroll
                    for (int j = 0; j < 4; ++j)
                        g[i][j] = fmaf(aa[i], bb[j], g[i][j]);
            }
        } else {
            for (int n = 0; n < 32; ++n) {
                float xv = xs[n][d_s * 16 + s_s];
                float nv = nrm[n][d_s];
                sx += xv;
                hh = fmaf(nv, xv, hh);
                if (s_s == 0) s2 = fmaf(nv, nv, s2);
            }
        }
        __syncthreads();
    }
    float* pb = partials + (size_t)b * ST;
    if (t < 128) {
        const int base = d_g * 256;
#pragma unroll
        for (int i = 0; i < 4; ++i)
#pragma unroll
            for (int j = 0; j < 4; ++j)
                pb[base + (r0 + i) * 16 + (c0 + j)] = g[i][j];
    } else {
        pb[2048 + d_s * 16 + s_s] = sx;
        pb[2176 + d_s * 16 + s_s] = hh;
        if (s_s == 0) pb[2304 + d_s] = s2;
    }
}

// ---- stage A: fold nb blocks down to 32, in place. grid (10, 32). ----
__global__ __launch_bounds__(256) void k2a_reduce(float* __restrict__ partials, int nb)
{
    const int idx = blockIdx.x * 256 + threadIdx.x;
    if (idx >= 2312) return;
    const int y = blockIdx.y;          // 0..31
    float acc[8] = {0.f, 0.f, 0.f, 0.f, 0.f, 0.f, 0.f, 0.f};
    int b = y;
    while (b + 7 * 32 < nb) {
#pragma unroll
        for (int u = 0; u < 8; ++u)
            acc[u] += partials[(size_t)(b + u * 32) * ST + idx];
        b += 8 * 32;
    }
    while (b < nb) { acc[0] += partials[(size_t)b * ST + idx]; b += 32; }
    float s = ((acc[0] + acc[1]) + (acc[2] + acc[3]))
            + ((acc[4] + acc[5]) + (acc[6] + acc[7]));
    partials[(size_t)y * ST + idx] = s;
}

// ---- stage B: sum the 32 survivors (L2-resident, fully unrolled). grid 10. ----
__global__ __launch_bounds__(256) void k2b_reduce(const float* __restrict__ partials,
                                                  float* __restrict__ stats)
{
    const int idx = blockIdx.x * 256 + threadIdx.x;
    if (idx >= 2312) return;
    float acc[8] = {0.f, 0.f, 0.f, 0.f, 0.f, 0.f, 0.f, 0.f};
#pragma unroll
    for (int j = 0; j < 4; ++j)
#pragma unroll
        for (int u = 0; u < 8; ++u)
            acc[u] += partials[(size_t)(j * 8 + u) * ST + idx];
    stats[idx] = ((acc[0] + acc[1]) + (acc[2] + acc[3]))
               + ((acc[4] + acc[5]) + (acc[6] + acc[7]));
}

__global__ __launch_bounds__(128) void k3_final(const float* __restrict__ stats,
                                                const float* __restrict__ centroids,
                                                float2* __restrict__ ab)
{
    __shared__ float st[2312];
    const int t = threadIdx.x;
    for (int i = t; i < 2312; i += 128) st[i] = stats[i];
    __syncthreads();
    const int k = t;   // 128 threads, one per code

    double Sn[8], Sn_tot = 0.0, S2_tot = 0.0;
#pragma unroll
    for (int d = 0; d < 8; ++d) {
        double s = 0.0;
        for (int ss = 0; ss < 16; ++ss) s += (double)st[d * 256 + ss * 17];
        Sn[d] = s; Sn_tot += s;
        S2_tot += (double)st[2304 + d];
    }
    double sr = -Sn_tot, sr2 = S2_tot;
    double ncd[8];
    for (int d = 0; d < 8; ++d) {
        const float* cp = centroids + d * 2048 + k * 16;
        float cv[16];
#pragma unroll
        for (int s = 0; s < 16; ++s) cv[s] = cp[s];
        double nc = 0, cdSx = 0, ch = 0, cGc = 0;
        for (int s = 0; s < 16; ++s) {
            nc   += (double)cv[s] * cv[s];
            cdSx += (double)cv[s] * st[2048 + d * 16 + s];
            ch   += (double)cv[s] * st[2176 + d * 16 + s];
            double rd = 0;
            for (int s2i = 0; s2i < 16; ++s2i)
                rd += (double)st[d * 256 + s * 16 + s2i] * cv[s2i];
            cGc += (double)cv[s] * rd;
        }
        ncd[d] = nc;
        sr  += 2.0 * cdSx - (double)NTOK * nc;
        sr2 += 4.0 * cGc + (double)NTOK * nc * nc + 2.0 * nc * Sn[d]
               - 4.0 * ch - 4.0 * nc * cdSx;
    }
    const double M = (double)NTOK * 8.0;
    double mean = sr / M;
    double var  = sr2 / M - mean * mean;
    float alpha = (float)(1.0 / sqrt(var + (double)EPS));
#pragma unroll
    for (int d = 0; d < 8; ++d) {
        float beta = (float)((double)alpha * (-ncd[d] - mean));
        ab[d * 128 + k] = make_float2(2.f * alpha, beta);
    }
}

// One token per thread, one d-PAIR per blockIdx.y. Centroids + (2a,b) for both
// d's staged in LDS; inner-loop reads are wave-uniform (same address across all
// 64 lanes -> broadcast, zero bank conflicts, no SMEM/lgkmcnt-drain pathology).
// 2048 blocks, ~18KB LDS, target 8 blocks/CU.
__global__ __launch_bounds__(256) void k4_main(const int* __restrict__ ids,
                                               const float* __restrict__ wemb,
                                               const float* __restrict__ centroids,
                                               const float2* __restrict__ ab,
                                               float* __restrict__ out)
{
    __shared__ float c0s[128][16];
    __shared__ float c1s[128][16];
    __shared__ float4 gbs[128];       // (2a0, b0, 2a1, b1) per k

    const int t = threadIdx.x;
    const int p = blockIdx.y;               // 0..3
    const int n = blockIdx.x * 256 + t;
    const int d0 = 2 * p;
    const float* cd0 = centroids + (size_t)d0 * 2048;
    const float* cd1 = cd0 + 2048;

    // stage centroids (2 x 8KB) + fused BN coefs (2KB)
#pragma unroll
    for (int i = 0; i < 2; ++i) {
        ((float4*)c0s)[t + i * 256] = ((const float4*)cd0)[t + i * 256];
        ((float4*)c1s)[t + i * 256] = ((const float4*)cd1)[t + i * 256];
    }
    if (t < 128) {
        float2 g0 = ab[(size_t)d0 * 128 + t];
        float2 g1 = ab[(size_t)d0 * 128 + 128 + t];
        gbs[t] = make_float4(g0.x, g0.y, g1.x, g1.y);
    }

    const float* xp = wemb + (size_t)ids[n] * 128 + d0 * 16;
    float x0[16], x1[16];
#pragma unroll
    for (int q = 0; q < 16; q += 4) {
        float4 v = *(const float4*)(xp + q);
        x0[q] = v.x; x0[q + 1] = v.y; x0[q + 2] = v.z; x0[q + 3] = v.w;
    }
#pragma unroll
    for (int q = 0; q < 16; q += 4) {
        float4 v = *(const float4*)(xp + 16 + q);
        x1[q] = v.x; x1[q + 1] = v.y; x1[q + 2] = v.z; x1[q + 3] = v.w;
    }
    float s0 = 0.f, s1 = 0.f;
#pragma unroll
    for (int q = 0; q < 16; ++q) { s0 = fmaf(x0[q], x0[q], s0); s1 = fmaf(x1[q], x1[q], s1); }
    const float nx0 = -0.5f * s0;      // score = 2a*(dot - nx/2) + beta
    const float nx1 = -0.5f * s1;
    float best0 = -3.4e38f, best1 = -3.4e38f;
    int code0 = 0, code1 = 0;

    __syncthreads();

#pragma unroll 2
    for (int k = 0; k < 128; ++k) {
        // wave-uniform LDS reads -> broadcast, scheduled ahead by unroll-2
        float4 a0 = *(const float4*)(&c0s[k][0]);
        float4 a1 = *(const float4*)(&c0s[k][4]);
        float4 a2 = *(const float4*)(&c0s[k][8]);
        float4 a3 = *(const float4*)(&c0s[k][12]);
        float4 b0 = *(const float4*)(&c1s[k][0]);
        float4 b1 = *(const float4*)(&c1s[k][4]);
        float4 b2 = *(const float4*)(&c1s[k][8]);
        float4 b3 = *(const float4*)(&c1s[k][12]);
        float4 g  = gbs[k];
        float ca[16] = {a0.x, a0.y, a0.z, a0.w, a1.x, a1.y, a1.z, a1.w,
                        a2.x, a2.y, a2.z, a2.w, a3.x, a3.y, a3.z, a3.w};
        float cb[16] = {b0.x, b0.y, b0.z, b0.w, b1.x, b1.y, b1.z, b1.w,
                        b2.x, b2.y, b2.z, b2.w, b3.x, b3.y, b3.z, b3.w};
        float acc0 = nx0, acc1 = nx1;
#pragma unroll
        for (int q = 0; q < 16; ++q) {
            acc0 = fmaf(ca[q], x0[q], acc0);
            acc1 = fmaf(cb[q], x1[q], acc1);
        }
        float sc0 = fmaf(g.x, acc0, g.y);
        float sc1 = fmaf(g.z, acc1, g.w);
        bool p0 = sc0 > best0;              // strict > keeps FIRST max (argmax tie rule)
        bool p1 = sc1 > best1;
        best0 = p0 ? sc0 : best0;  code0 = p0 ? k : code0;
        best1 = p1 ? sc1 : best1;  code1 = p1 ? k : code1;
    }

    // winning centroids from LDS (divergent address, but 2-way max aliasing ok)
    const float* w0 = &c0s[code0][0];
    const float* w1 = &c1s[code1][0];
    float* op = out + (size_t)n * 128 + d0 * 16;
#pragma unroll
    for (int q = 0; q < 16; q += 4) {
        float4 cv = *(const float4*)(w0 + q);
        float4 o;
        // match reference: out = x + (c - x) in fp32 (not just c)
        o.x = x0[q + 0] + (cv.x - x0[q + 0]);
        o.y = x0[q + 1] + (cv.y - x0[q + 1]);
        o.z = x0[q + 2] + (cv.z - x0[q + 2]);
        o.w = x0[q + 3] + (cv.w - x0[q + 3]);
        *(float4*)(op + q) = o;
    }
#pragma unroll
    for (int q = 0; q < 16; q += 4) {
        float4 cv = *(const float4*)(w1 + q);
        float4 o;
        o.x = x1[q + 0] + (cv.x - x1[q + 0]);
        o.y = x1[q + 1] + (cv.y - x1[q + 1]);
        o.z = x1[q + 2] + (cv.z - x1[q + 2]);
        o.w = x1[q + 3] + (cv.w - x1[q + 3]);
        *(float4*)(op + 16 + q) = o;
    }
}

extern "C" void kernel_launch(void* const* d_in, const int* in_sizes, int n_in,
                              void* d_out, int out_size, void* d_ws, size_t ws_size,
                              hipStream_t stream)
{
    const int* ids    = (const int*)d_in[0];
    const float* wemb = (const float*)d_in[1];
    const float* cent = (const float*)d_in[2];
    float* out = (float*)d_out;
    float* ws  = (float*)d_ws;

    // choose pass-1 block count by available workspace
    int p1b = 1024;
    if (ws_size < ((size_t)1024 * ST + 2320 + 2048) * 4) p1b = 512;
    if (ws_size < ((size_t)512  * ST + 2320 + 2048) * 4) p1b = 256;
    if (ws_size < ((size_t)256  * ST + 2320 + 2048) * 4) p1b = 128;
    const int tpb = NTOK / p1b;

    float* partials = ws;
    float* stats    = ws + (size_t)p1b * ST;
    float2* ab      = (float2*)(stats + 2320);

    hipLaunchKernelGGL(k1_stats,   dim3(p1b),     dim3(256), 0, stream, ids, wemb, partials, tpb);
    hipLaunchKernelGGL(k2a_reduce, dim3(10, 32),  dim3(256), 0, stream, partials, p1b);
    hipLaunchKernelGGL(k2b_reduce, dim3(10),      dim3(256), 0, stream, partials, stats);
    hipLaunchKernelGGL(k3_final,   dim3(1),       dim3(128), 0, stream, stats, cent, ab);
    hipLaunchKernelGGL(k4_main,    dim3(512, 4),  dim3(256), 0, stream, ids, wemb, cent, ab, out);
}

// Round 6
// 148.944 us; speedup vs baseline: 1.1228x; 1.0495x over previous
//
#include <hip/hip_runtime.h>

// DPQ embedding, MI355X. N=131072 tokens, EMB=128, D=8 subspaces x SUB=16, K=128 codes.
// Pipeline:
//  k1_stats:  gather x rows, accumulate per-block moment stats (G, Sx, h, Sn, S2)
//  k2a/k2b:   deterministic two-stage tree-reduce of block partials (in-place)
//  k3_final:  stats + centroids -> alpha[k], beta[d][k]  (BN folded into affine score)
//  k4_main:   8 tokens/thread, one d/block. Centroid k-row read ONCE per k per
//             thread (uniform LDS broadcast) and reused for 8 tokens -> DS-issue
//             per token-d is 14x lower than R5. FMAs written directly on float4
//             components (R5's local c[16] arrays generated v_mov unpack storms).
// History: R2 88us (LDS, 4-token amortize, occupancy-limited); R3 103us (SMEM 1
// stream); R4 126us (SMEM 2 streams, lgkmcnt drain); R5 123us (LDS d-pair,
// DS-issue bound: 9.4M ds_read_b128 x 8cyc / 256CU == 123us measured).

constexpr int NTOK = 131072;   // 1024*128
constexpr int ST   = 2320;     // stats stride (2312 used, padded)
constexpr float EPS = 0.001f;

// stats layout: G: d*256 + s*16 + s'  (2048)
//               Sx: 2048 + d*16 + s   (128)
//               h : 2176 + d*16 + s   (128)
//               S2: 2304 + d          (8)    -> 2312 total

__global__ __launch_bounds__(256) void k1_stats(const int* __restrict__ ids,
                                                const float* __restrict__ wemb,
                                                float* __restrict__ partials,
                                                int tpb)
{
    __shared__ float xs[32][132];   // 32 tokens x 128 floats, padded to 132
    __shared__ float nrm[32][8];
    const int t = threadIdx.x;
    const int b = blockIdx.x;

    float g[4][4];
#pragma unroll
    for (int i = 0; i < 4; ++i)
#pragma unroll
        for (int j = 0; j < 4; ++j) g[i][j] = 0.f;
    float sx = 0.f, hh = 0.f, s2 = 0.f;

    const int d_g = t >> 4;                 // t<128: Gram task (d, 4x4 tile)
    const int r0  = ((t >> 2) & 3) << 2;
    const int c0  = (t & 3) << 2;
    const int u   = t & 127;                // t>=128: (d,s) task
    const int d_s = u >> 4;
    const int s_s = u & 15;

    const int nchunks = tpb >> 5;
    for (int ch = 0; ch < nchunks; ++ch) {
        const int n0 = b * tpb + ch * 32;
        // ---- load 32 token rows (coalesced: 32 lanes x float4 = one 512B row) ----
#pragma unroll
        for (int rep = 0; rep < 4; ++rep) {
            int i = t + rep * 256;
            int n = i >> 5, f = i & 31;
            int id = ids[n0 + n];
            float4 v = *(const float4*)(wemb + (size_t)id * 128 + f * 4);
            *(float4*)(&xs[n][f * 4]) = v;
        }
        __syncthreads();
        // ---- per-(n,d) norms: 256 threads = 32x8 ----
        {
            int n = t >> 3, dd = t & 7;
            const float* xp = &xs[n][dd * 16];
            float4 a = *(const float4*)(xp);
            float4 bq = *(const float4*)(xp + 4);
            float4 c = *(const float4*)(xp + 8);
            float4 dq = *(const float4*)(xp + 12);
            float acc = a.x*a.x + a.y*a.y + a.z*a.z + a.w*a.w;
            acc += bq.x*bq.x + bq.y*bq.y + bq.z*bq.z + bq.w*bq.w;
            acc += c.x*c.x + c.y*c.y + c.z*c.z + c.w*c.w;
            acc += dq.x*dq.x + dq.y*dq.y + dq.z*dq.z + dq.w*dq.w;
            nrm[n][dd] = acc;
        }
        __syncthreads();
        // ---- accumulate stats over the chunk ----
        if (t < 128) {
            for (int n = 0; n < 32; ++n) {
                const float* xp = &xs[n][d_g * 16];
                float4 av = *(const float4*)(xp + r0);
                float4 bv = *(const float4*)(xp + c0);
                float aa[4] = {av.x, av.y, av.z, av.w};
                float bb[4] = {bv.x, bv.y, bv.z, bv.w};
#pragma unroll
                for (int i = 0; i < 4; ++i)
#pragma unroll
                    for (int j = 0; j < 4; ++j)
                        g[i][j] = fmaf(aa[i], bb[j], g[i][j]);
            }
        } else {
            for (int n = 0; n < 32; ++n) {
                float xv = xs[n][d_s * 16 + s_s];
                float nv = nrm[n][d_s];
                sx += xv;
                hh = fmaf(nv, xv, hh);
                if (s_s == 0) s2 = fmaf(nv, nv, s2);
            }
        }
        __syncthreads();
    }
    float* pb = partials + (size_t)b * ST;
    if (t < 128) {
        const int base = d_g * 256;
#pragma unroll
        for (int i = 0; i < 4; ++i)
#pragma unroll
            for (int j = 0; j < 4; ++j)
                pb[base + (r0 + i) * 16 + (c0 + j)] = g[i][j];
    } else {
        pb[2048 + d_s * 16 + s_s] = sx;
        pb[2176 + d_s * 16 + s_s] = hh;
        if (s_s == 0) pb[2304 + d_s] = s2;
    }
}

// ---- stage A: fold nb blocks down to 32, in place. grid (10, 32). ----
__global__ __launch_bounds__(256) void k2a_reduce(float* __restrict__ partials, int nb)
{
    const int idx = blockIdx.x * 256 + threadIdx.x;
    if (idx >= 2312) return;
    const int y = blockIdx.y;          // 0..31
    float acc[8] = {0.f, 0.f, 0.f, 0.f, 0.f, 0.f, 0.f, 0.f};
    int b = y;
    while (b + 7 * 32 < nb) {
#pragma unroll
        for (int u = 0; u < 8; ++u)
            acc[u] += partials[(size_t)(b + u * 32) * ST + idx];
        b += 8 * 32;
    }
    while (b < nb) { acc[0] += partials[(size_t)b * ST + idx]; b += 32; }
    float s = ((acc[0] + acc[1]) + (acc[2] + acc[3]))
            + ((acc[4] + acc[5]) + (acc[6] + acc[7]));
    partials[(size_t)y * ST + idx] = s;
}

// ---- stage B: sum the 32 survivors (L2-resident, fully unrolled). grid 10. ----
__global__ __launch_bounds__(256) void k2b_reduce(const float* __restrict__ partials,
                                                  float* __restrict__ stats)
{
    const int idx = blockIdx.x * 256 + threadIdx.x;
    if (idx >= 2312) return;
    float acc[8] = {0.f, 0.f, 0.f, 0.f, 0.f, 0.f, 0.f, 0.f};
#pragma unroll
    for (int j = 0; j < 4; ++j)
#pragma unroll
        for (int u = 0; u < 8; ++u)
            acc[u] += partials[(size_t)(j * 8 + u) * ST + idx];
    stats[idx] = ((acc[0] + acc[1]) + (acc[2] + acc[3]))
               + ((acc[4] + acc[5]) + (acc[6] + acc[7]));
}

__global__ __launch_bounds__(128) void k3_final(const float* __restrict__ stats,
                                                const float* __restrict__ centroids,
                                                float2* __restrict__ ab)
{
    __shared__ float st[2312];
    const int t = threadIdx.x;
    for (int i = t; i < 2312; i += 128) st[i] = stats[i];
    __syncthreads();
    const int k = t;   // 128 threads, one per code

    double Sn[8], Sn_tot = 0.0, S2_tot = 0.0;
#pragma unroll
    for (int d = 0; d < 8; ++d) {
        double s = 0.0;
        for (int ss = 0; ss < 16; ++ss) s += (double)st[d * 256 + ss * 17];
        Sn[d] = s; Sn_tot += s;
        S2_tot += (double)st[2304 + d];
    }
    double sr = -Sn_tot, sr2 = S2_tot;
    double ncd[8];
    for (int d = 0; d < 8; ++d) {
        const float* cp = centroids + d * 2048 + k * 16;
        float cv[16];
#pragma unroll
        for (int s = 0; s < 16; ++s) cv[s] = cp[s];
        double nc = 0, cdSx = 0, ch = 0, cGc = 0;
        for (int s = 0; s < 16; ++s) {
            nc   += (double)cv[s] * cv[s];
            cdSx += (double)cv[s] * st[2048 + d * 16 + s];
            ch   += (double)cv[s] * st[2176 + d * 16 + s];
            double rd = 0;
            for (int s2i = 0; s2i < 16; ++s2i)
                rd += (double)st[d * 256 + s * 16 + s2i] * cv[s2i];
            cGc += (double)cv[s] * rd;
        }
        ncd[d] = nc;
        sr  += 2.0 * cdSx - (double)NTOK * nc;
        sr2 += 4.0 * cGc + (double)NTOK * nc * nc + 2.0 * nc * Sn[d]
               - 4.0 * ch - 4.0 * nc * cdSx;
    }
    const double M = (double)NTOK * 8.0;
    double mean = sr / M;
    double var  = sr2 / M - mean * mean;
    float alpha = (float)(1.0 / sqrt(var + (double)EPS));
#pragma unroll
    for (int d = 0; d < 8; ++d) {
        float beta = (float)((double)alpha * (-ncd[d] - mean));
        ab[d * 128 + k] = make_float2(2.f * alpha, beta);
    }
}

// 8 tokens per thread, one d per blockIdx.y, 128-thread blocks (2 waves).
// Per k-iteration: 4 uniform ds_read_b128 + 1 ds_read_b64 serve 8 token-d
// (0.625 DS/token-d). Inner FMAs use float4 components directly (no unpack
// arrays). Winner centroid re-read from GLOBAL (8KB, L1-hot) so the k-loop LDS
// stays conflict-free. 1024 blocks -> 4 blocks/CU, 8 waves/CU.
__global__ __launch_bounds__(128) void k4_main(const int* __restrict__ ids,
                                               const float* __restrict__ wemb,
                                               const float* __restrict__ centroids,
                                               const float2* __restrict__ ab,
                                               float* __restrict__ out)
{
    __shared__ float  cs[128 * 16];   // 8KB: centroids for this d
    __shared__ float2 gbs[128];       // (2*alpha, beta)

    const int t = threadIdx.x;        // 0..127
    const int d = blockIdx.y;
    const float* cd = centroids + (size_t)d * 2048;

    // stage: 2048 floats = 512 float4 -> 4 per thread; 1 gb each
#pragma unroll
    for (int i = 0; i < 4; ++i)
        ((float4*)cs)[t + i * 128] = ((const float4*)cd)[t + i * 128];
    gbs[t] = ab[(size_t)d * 128 + t];

    const int nbase = blockIdx.x * 1024 + t;   // 8 tokens, stride 128
    float x[8][16];
    float nx[8], best[8];
    int   code[8];
#pragma unroll
    for (int j = 0; j < 8; ++j) {
        const int n = nbase + j * 128;
        const float* xp = wemb + (size_t)ids[n] * 128 + d * 16;
#pragma unroll
        for (int q = 0; q < 16; q += 4) {
            float4 v = *(const float4*)(xp + q);
            x[j][q] = v.x; x[j][q + 1] = v.y; x[j][q + 2] = v.z; x[j][q + 3] = v.w;
        }
        float s = 0.f;
#pragma unroll
        for (int q = 0; q < 16; ++q) s = fmaf(x[j][q], x[j][q], s);
        nx[j] = -0.5f * s;             // score = 2a*(dot - nx/2) + beta
        best[j] = -3.4e38f;
        code[j] = 0;
    }

    __syncthreads();

#pragma unroll 2
    for (int k = 0; k < 128; ++k) {
        // wave-uniform broadcast reads (no conflicts, 5 DS ops for 8 token-d)
        const float4 c0 = *(const float4*)(&cs[k * 16 + 0]);
        const float4 c1 = *(const float4*)(&cs[k * 16 + 4]);
        const float4 c2 = *(const float4*)(&cs[k * 16 + 8]);
        const float4 c3 = *(const float4*)(&cs[k * 16 + 12]);
        const float2 g  = gbs[k];
#pragma unroll
        for (int j = 0; j < 8; ++j) {
            float acc = nx[j];
            acc = fmaf(c0.x, x[j][0],  acc);
            acc = fmaf(c0.y, x[j][1],  acc);
            acc = fmaf(c0.z, x[j][2],  acc);
            acc = fmaf(c0.w, x[j][3],  acc);
            acc = fmaf(c1.x, x[j][4],  acc);
            acc = fmaf(c1.y, x[j][5],  acc);
            acc = fmaf(c1.z, x[j][6],  acc);
            acc = fmaf(c1.w, x[j][7],  acc);
            acc = fmaf(c2.x, x[j][8],  acc);
            acc = fmaf(c2.y, x[j][9],  acc);
            acc = fmaf(c2.z, x[j][10], acc);
            acc = fmaf(c2.w, x[j][11], acc);
            acc = fmaf(c3.x, x[j][12], acc);
            acc = fmaf(c3.y, x[j][13], acc);
            acc = fmaf(c3.z, x[j][14], acc);
            acc = fmaf(c3.w, x[j][15], acc);
            float sc = fmaf(g.x, acc, g.y);
            bool p = sc > best[j];         // strict > keeps FIRST max (argmax tie rule)
            best[j] = p ? sc : best[j];
            code[j] = p ? k : code[j];
        }
    }

#pragma unroll
    for (int j = 0; j < 8; ++j) {
        const int n = nbase + j * 128;
        const float* cw = cd + code[j] * 16;   // global, L1-hot 8KB set
        float* op = out + (size_t)n * 128 + d * 16;
#pragma unroll
        for (int q = 0; q < 16; q += 4) {
            float4 cv = *(const float4*)(cw + q);
            float4 o;
            // match reference: out = x + (c - x) in fp32 (not just c)
            o.x = x[j][q + 0] + (cv.x - x[j][q + 0]);
            o.y = x[j][q + 1] + (cv.y - x[j][q + 1]);
            o.z = x[j][q + 2] + (cv.z - x[j][q + 2]);
            o.w = x[j][q + 3] + (cv.w - x[j][q + 3]);
            *(float4*)(op + q) = o;
        }
    }
}

extern "C" void kernel_launch(void* const* d_in, const int* in_sizes, int n_in,
                              void* d_out, int out_size, void* d_ws, size_t ws_size,
                              hipStream_t stream)
{
    const int* ids    = (const int*)d_in[0];
    const float* wemb = (const float*)d_in[1];
    const float* cent = (const float*)d_in[2];
    float* out = (float*)d_out;
    float* ws  = (float*)d_ws;

    // choose pass-1 block count by available workspace
    int p1b = 1024;
    if (ws_size < ((size_t)1024 * ST + 2320 + 2048) * 4) p1b = 512;
    if (ws_size < ((size_t)512  * ST + 2320 + 2048) * 4) p1b = 256;
    if (ws_size < ((size_t)256  * ST + 2320 + 2048) * 4) p1b = 128;
    const int tpb = NTOK / p1b;

    float* partials = ws;
    float* stats    = ws + (size_t)p1b * ST;
    float2* ab      = (float2*)(stats + 2320);

    hipLaunchKernelGGL(k1_stats,   dim3(p1b),     dim3(256), 0, stream, ids, wemb, partials, tpb);
    hipLaunchKernelGGL(k2a_reduce, dim3(10, 32),  dim3(256), 0, stream, partials, p1b);
    hipLaunchKernelGGL(k2b_reduce, dim3(10),      dim3(256), 0, stream, partials, stats);
    hipLaunchKernelGGL(k3_final,   dim3(1),       dim3(128), 0, stream, stats, cent, ab);
    hipLaunchKernelGGL(k4_main,    dim3(128, 8),  dim3(128), 0, stream, ids, wemb, cent, ab, out);
}